// Round 4
// baseline (111.787 us; speedup 1.0000x reference)
//
#include <hip/hip_runtime.h>
#include <stdint.h>

typedef __bf16 bf16_t;
typedef bf16_t __attribute__((ext_vector_type(8))) bf16x8;
typedef float __attribute__((ext_vector_type(4))) f32x4;
typedef float __attribute__((ext_vector_type(16))) f32x16;
typedef unsigned u32;

#define BATCH 4
#define SEQ 1024
#define HIDD 1024
#define NH 16
#define DH 64

// ---------- helpers ----------
__device__ __forceinline__ unsigned short f2bf(float f) {
  unsigned u = __float_as_uint(f);
  u += 0x7fffu + ((u >> 16) & 1u);   // RNE
  return (unsigned short)(u >> 16);
}

__device__ __forceinline__ f32x4 mfma16(bf16x8 a, bf16x8 b, f32x4 c) {
  return __builtin_amdgcn_mfma_f32_16x16x32_bf16(a, b, c, 0, 0, 0);
}
__device__ __forceinline__ f32x16 mfma32(bf16x8 a, bf16x8 b, f32x16 c) {
  return __builtin_amdgcn_mfma_f32_32x32x16_bf16(a, b, c, 0, 0, 0);
}

__device__ __forceinline__ void gload_lds16(const void* g, void* l) {
  __builtin_amdgcn_global_load_lds(
      (__attribute__((address_space(1))) void*)(uintptr_t)g,
      (__attribute__((address_space(3))) void*)l, 16, 0, 0);
}

__device__ __forceinline__ u32 cvtpk(float lo, float hi) {
  u32 r;
  asm("v_cvt_pk_bf16_f32 %0, %1, %2" : "=v"(r) : "v"(lo), "v"(hi));
  return r;
}
__device__ __forceinline__ void plswap(u32& a, u32& b) {
  asm("v_permlane32_swap_b32 %0, %1" : "+v"(a), "+v"(b));
}

// ---------- kernel 1: hidden_states fp32 -> bf16 ----------
__global__ void hs2bf(const float* __restrict__ x, unsigned short* __restrict__ y) {
  const int i = blockIdx.x * 256 + threadIdx.x;
  const float4 f = ((const float4*)x)[i];
  ushort4 o = make_ushort4(f2bf(f.x), f2bf(f.y), f2bf(f.z), f2bf(f.w));
  ((ushort4*)y)[i] = o;
}

// ---------- kernel 2: W (K x N) fp32 -> Wt (N x K) bf16 ----------
__global__ __launch_bounds__(256) void wtrans(
    const float* __restrict__ Wq, const float* __restrict__ Wk,
    const float* __restrict__ Wv, unsigned short* __restrict__ Wt) {
  __shared__ unsigned short tile[64][72];
  const int z = blockIdx.z;
  const float* W = (z == 0) ? Wq : (z == 1) ? Wk : Wv;
  unsigned short* o = Wt + (size_t)z * (1024 * 1024);
  const int k0 = blockIdx.x * 64, n0 = blockIdx.y * 64;
  const int r = threadIdx.x >> 6, c = threadIdx.x & 63;
#pragma unroll
  for (int i = 0; i < 16; ++i) {
    const int row = i * 4 + r;
    tile[row][c] = f2bf(W[(size_t)(k0 + row) * 1024 + n0 + c]);
  }
  __syncthreads();
#pragma unroll
  for (int i = 0; i < 16; ++i) {
    const int row = i * 4 + r;
    o[(size_t)(n0 + row) * 1024 + k0 + c] = tile[c][row];
  }
}

// ---------- kernel 3: QKV projection GEMM ----------
__global__ __launch_bounds__(256) void qkv_gemm(
    const unsigned short* __restrict__ A,
    const unsigned short* __restrict__ Wt,
    const float* __restrict__ bq, const float* __restrict__ bk,
    const float* __restrict__ bv,
    unsigned short* __restrict__ outb) {
  __shared__ alignas(16) unsigned short Alds[128 * 32];
  __shared__ alignas(16) unsigned short Blds[128 * 32];

  const int z = blockIdx.z;
  const unsigned short* Bt = Wt + (size_t)z * (1024 * 1024);
  const float* bias = (z == 0) ? bq : (z == 1) ? bk : bv;
  unsigned short* outp = outb + (size_t)z * (4096 * 1024);
  const float scale = (z == 0) ? 0.125f * 1.44269504089f : 1.0f; // exp2 domain for Q

  const int m0 = blockIdx.x * 128;
  const int n0 = blockIdx.y * 128;
  const int t = threadIdx.x;
  const int w = t >> 6, l = t & 63;
  const int lg = l >> 4, lc = l & 15;
  const int wr = w >> 1, wc = w & 1;

  f32x4 acc[4][4] = {};

  for (int kt = 0; kt < 1024; kt += 32) {
    __syncthreads();
#pragma unroll
    for (int i = 0; i < 2; ++i) {
      const int c = i * 256 + t;
      const int row = c >> 2;
      const int kp = (c & 3) * 8;
      gload_lds16(A + (size_t)(m0 + row) * 1024 + kt + kp,
                  (char*)Alds + i * 4096 + w * 1024);
      gload_lds16(Bt + (size_t)(n0 + row) * 1024 + kt + kp,
                  (char*)Blds + i * 4096 + w * 1024);
    }
    __syncthreads();

    bf16x8 af[4], bfr[4];
#pragma unroll
    for (int m = 0; m < 4; ++m)
      af[m] = *(const bf16x8*)(Alds + (wr * 64 + m * 16 + lc) * 32 + lg * 8);
#pragma unroll
    for (int n = 0; n < 4; ++n)
      bfr[n] = *(const bf16x8*)(Blds + (wc * 64 + n * 16 + lc) * 32 + lg * 8);
#pragma unroll
    for (int m = 0; m < 4; ++m)
#pragma unroll
      for (int n = 0; n < 4; ++n)
        acc[m][n] = mfma16(af[m], bfr[n], acc[m][n]);
  }

#pragma unroll
  for (int n = 0; n < 4; ++n) {
    const int col = n0 + wc * 64 + n * 16 + lc;
    const float bs = bias[col];
#pragma unroll
    for (int m = 0; m < 4; ++m)
#pragma unroll
      for (int r = 0; r < 4; ++r) {
        const int row = m0 + wr * 64 + m * 16 + lg * 4 + r;
        outp[(size_t)row * 1024 + col] = f2bf((acc[m][n][r] + bs) * scale);
      }
  }
}

// ---------- kernel 3.5: V -> Vt (B,H,D,S) ----------
__global__ __launch_bounds__(256) void vtrans(
    const unsigned short* __restrict__ V, unsigned short* __restrict__ Vt) {
  __shared__ unsigned short tile[64][72];
  const int tt = blockIdx.x;
  const int hh = blockIdx.y;
  const int t = threadIdx.x;
#pragma unroll
  for (int i = 0; i < 2; ++i) {
    const int c = i * 256 + t;
    const int row = c >> 3, cp = c & 7;
    *(uint4*)&tile[row][cp * 8] =
        *(const uint4*)(V + (size_t)(tt * 64 + row) * 1024 + hh * 64 + cp * 8);
  }
  __syncthreads();
  const int b = (tt * 64) >> 10, s0 = (tt * 64) & 1023;
  const int d = t >> 2, toff = (t & 3) * 16;
  unsigned short buf[16];
#pragma unroll
  for (int e = 0; e < 16; ++e) buf[e] = tile[toff + e][d];
  unsigned short* dst = Vt + ((size_t)(b * NH + hh) * DH + d) * SEQ + s0 + toff;
  *(uint4*)dst = *(uint4*)buf;
  *(uint4*)(dst + 8) = *(uint4*)(buf + 8);
}

// ---------- kernel 4: flash attention, direct global->register, barrier-free ----------
// grid 512 (XCD-swizzled); block 256 = 4 independent waves, each owns 32 q-rows.
// S^T = mfma32(K, Q^T): C col=lane&31=qrow, row=key=(reg&3)+8*(reg>>2)+4*(lane>>5).
// No LDS, no __syncthreads: per-lane 16B fragment loads straight from L2.
__global__ __launch_bounds__(256, 2) void attn_kernel(
    const unsigned short* __restrict__ Qb,  // (B,S,H,D) bf16, pre-scaled log2e/sqrt(D)
    const unsigned short* __restrict__ Kb,  // (B,S,H,D) bf16
    const unsigned short* __restrict__ Vt,  // (B,H,D,S) bf16
    const int* __restrict__ amask,          // (B,S)
    const float* __restrict__ lhm,          // (H)
    float* __restrict__ out) {              // (B,S,HID) fp32
  const int id = blockIdx.x;
  const int swzid = (id & 7) * 64 + (id >> 3);  // 8 bh per XCD
  const int qt = swzid & 7;
  const int bh = swzid >> 3;
  const int b = bh >> 4, h = bh & 15;
  const int t = threadIdx.x;
  const int w = t >> 6, l = t & 63;
  const int lo = l & 31, hi = l >> 5;
  const int q0 = qt * 128 + w * 32;

  // per-lane fragment base pointers
  // K frag (A-op): lane holds K[key = k0 + g*32 + lo][d = s*16 + hi*8 + e]
  const unsigned short* Kp = Kb + (size_t)(b * SEQ + lo) * HIDD + h * DH + hi * 8;
  // V frag (B-op): lane holds Vt[d = g*32 + lo][key = k0 + s*16 + hi*8 + e]
  const unsigned short* Vp = Vt + ((size_t)bh * DH + lo) * SEQ + hi * 8;

  // Q fragments (B-op): lane holds Q[q0+lo][d = s*16 + hi*8 + e]
  const unsigned short* qp = Qb + (size_t)(b * SEQ + q0 + lo) * HIDD + h * DH + hi * 8;
  bf16x8 qf[4];
#pragma unroll
  for (int s = 0; s < 4; ++s) qf[s] = *(const bf16x8*)(qp + s * 16);

  // mask precheck: one pass over batch b's mask (common case: all ones)
  bool needmask;
  {
    unsigned long long mm = ~0ull;
#pragma unroll
    for (int tk = 0; tk < 16; ++tk)
      mm &= __ballot(amask[b * SEQ + tk * 64 + l] > 0);
    needmask = (mm != ~0ull);
  }

  float m_run = -INFINITY, l_run = 0.f;
  f32x16 acc0 = {}, acc1 = {};

  bf16x8 kf0[4], kf1[4], vf0[4], vf1[4];

  // prefetch K tile 0
#pragma unroll
  for (int s = 0; s < 4; ++s) {
    kf0[s] = *(const bf16x8*)(Kp + (size_t)(0) * HIDD + s * 16);
    kf1[s] = *(const bf16x8*)(Kp + (size_t)(32) * HIDD + s * 16);
  }

  for (int tk = 0; tk < 16; ++tk) {
    const int k0 = tk * 64;

    // issue V loads for this tile (consumed after softmax -> latency hidden)
#pragma unroll
    for (int s = 0; s < 4; ++s) {
      vf0[s] = *(const bf16x8*)(Vp + k0 + s * 16);
      vf1[s] = *(const bf16x8*)(Vp + 32 * SEQ + k0 + s * 16);
    }

    // ---- S^T = K . Q^T ----
    f32x16 sg0 = {}, sg1 = {};
    __builtin_amdgcn_s_setprio(1);
#pragma unroll
    for (int s = 0; s < 4; ++s) {
      sg0 = mfma32(kf0[s], qf[s], sg0);
      sg1 = mfma32(kf1[s], qf[s], sg1);
    }
    __builtin_amdgcn_s_setprio(0);

    // prefetch K for next tile (hidden under softmax + PV)
    if (tk < 15) {
#pragma unroll
      for (int s = 0; s < 4; ++s) {
        kf0[s] = *(const bf16x8*)(Kp + (size_t)(k0 + 64) * HIDD + s * 16);
        kf1[s] = *(const bf16x8*)(Kp + (size_t)(k0 + 96) * HIDD + s * 16);
      }
    }

    // ---- row max ----
    float t0[8];
#pragma unroll
    for (int i = 0; i < 8; ++i)
      t0[i] = fmaxf(fmaxf(sg0[i], sg0[i + 8]), fmaxf(sg1[i], sg1[i + 8]));
    float t1 = fmaxf(fmaxf(fmaxf(t0[0], t0[1]), fmaxf(t0[2], t0[3])),
                     fmaxf(fmaxf(t0[4], t0[5]), fmaxf(t0[6], t0[7])));
    const float pmax = fmaxf(t1, __shfl_xor(t1, 32));

    // ---- defer-max (T13) ----
    if (!__all(pmax <= m_run + 8.f)) {
      const float mnew = fmaxf(m_run, pmax);
      const float sc = __builtin_amdgcn_exp2f(m_run - mnew);
      m_run = mnew;
      l_run *= sc;
#pragma unroll
      for (int g = 0; g < 16; ++g) {
        const int rowi = (g & 3) + 8 * (g >> 2) + 4 * hi;
        const float scr = __shfl(sc, rowi);
        acc0[g] *= scr;
        acc1[g] *= scr;
      }
    }

    // ---- p = exp2(s - m) ----
#pragma unroll
    for (int g = 0; g < 16; ++g) {
      sg0[g] = __builtin_amdgcn_exp2f(sg0[g] - m_run);
      sg1[g] = __builtin_amdgcn_exp2f(sg1[g] - m_run);
    }

    // ---- mask (slow path only; softmax invariant to max ref) ----
    if (needmask) {
      const int mv = amask[b * SEQ + k0 + l];
      const unsigned long long m64 = __ballot(mv > 0);
      if (m64 != ~0ull) {
#pragma unroll
        for (int g = 0; g < 16; ++g) {
          const int krow = (g & 3) + 8 * (g >> 2) + 4 * hi;
          if (!((m64 >> krow) & 1)) sg0[g] = 0.f;
          if (!((m64 >> (krow + 32)) & 1)) sg1[g] = 0.f;
        }
      }
    }

    // ---- row sum ----
    float s0[8];
#pragma unroll
    for (int i = 0; i < 8; ++i)
      s0[i] = (sg0[i] + sg0[i + 8]) + (sg1[i] + sg1[i + 8]);
    float rs = ((s0[0] + s0[1]) + (s0[2] + s0[3])) +
               ((s0[4] + s0[5]) + (s0[6] + s0[7]));
    rs += __shfl_xor(rs, 32);
    l_run += rs;

    // ---- P -> bf16 PA fragments in-register (T12) ----
    auto mk = [](float a0, float a1, float a2, float a3,
                 float a4, float a5, float a6, float a7) -> bf16x8 {
      u32 x = cvtpk(a0, a1), y = cvtpk(a2, a3);
      u32 a = cvtpk(a4, a5), b2 = cvtpk(a6, a7);
      plswap(x, a);
      plswap(y, b2);
      union { u32 u[4]; bf16x8 v; } fu;
      fu.u[0] = x; fu.u[1] = y; fu.u[2] = a; fu.u[3] = b2;
      return fu.v;
    };
    const bf16x8 pa0 = mk(sg0[0], sg0[1], sg0[2], sg0[3], sg0[4], sg0[5], sg0[6], sg0[7]);
    const bf16x8 pa1 = mk(sg0[8], sg0[9], sg0[10], sg0[11], sg0[12], sg0[13], sg0[14], sg0[15]);
    const bf16x8 pa2 = mk(sg1[0], sg1[1], sg1[2], sg1[3], sg1[4], sg1[5], sg1[6], sg1[7]);
    const bf16x8 pa3 = mk(sg1[8], sg1[9], sg1[10], sg1[11], sg1[12], sg1[13], sg1[14], sg1[15]);

    // ---- PV: acc += P . V ----
    __builtin_amdgcn_s_setprio(1);
#pragma unroll
    for (int s = 0; s < 4; ++s) {
      const bf16x8 paf = (s == 0) ? pa0 : (s == 1) ? pa1 : (s == 2) ? pa2 : pa3;
      acc0 = mfma32(paf, vf0[s], acc0);
      acc1 = mfma32(paf, vf1[s], acc1);
    }
    __builtin_amdgcn_s_setprio(0);
  }

  // ---- epilogue ----
  const float hm = lhm[h];
  const float inv = hm / l_run;
  float* ob = out + (size_t)(b * SEQ + q0) * HIDD + h * DH + lo;
#pragma unroll
  for (int g = 0; g < 16; ++g) {
    const int rowi = (g & 3) + 8 * (g >> 2) + 4 * hi;
    const float iv = __shfl(inv, rowi);
    ob[(size_t)rowi * HIDD] = acc0[g] * iv;
    ob[(size_t)rowi * HIDD + 32] = acc1[g] * iv;
  }
}

// ---------- launch ----------
extern "C" void kernel_launch(void* const* d_in, const int* in_sizes, int n_in,
                              void* d_out, int out_size, void* d_ws, size_t ws_size,
                              hipStream_t stream) {
  const float* hs = (const float*)d_in[0];
  const int* amask = (const int*)d_in[1];
  const float* lhm = (const float*)d_in[2];
  const float* Wq = (const float*)d_in[3];
  const float* bq = (const float*)d_in[4];
  const float* Wk = (const float*)d_in[5];
  const float* bk = (const float*)d_in[6];
  const float* Wv = (const float*)d_in[7];
  const float* bv = (const float*)d_in[8];
  float* out = (float*)d_out;

  char* ws = (char*)d_ws;
  unsigned short* HSbf = (unsigned short*)ws;                   // 8 MB
  unsigned short* Wt = (unsigned short*)(ws + (8u << 20));      // 6 MB
  unsigned short* QKV = (unsigned short*)(ws + (14u << 20));    // 24 MB
  unsigned short* Vtr = (unsigned short*)(ws + (38u << 20));    // 8 MB

  hs2bf<<<4096, 256, 0, stream>>>(hs, HSbf);
  wtrans<<<dim3(16, 16, 3), 256, 0, stream>>>(Wq, Wk, Wv, Wt);
  qkv_gemm<<<dim3(32, 8, 3), 256, 0, stream>>>(HSbf, Wt, bq, bk, bv, QKV);
  vtrans<<<dim3(64, 16), 256, 0, stream>>>(QKV + (size_t)2 * 4096 * 1024, Vtr);
  attn_kernel<<<512, 256, 0, stream>>>(
      QKV, QKV + (size_t)4096 * 1024, Vtr, amask, lhm, out);
}

// Round 5
// 85.959 us; speedup vs baseline: 1.3005x; 1.3005x over previous
//
#include <hip/hip_runtime.h>
#include <stdint.h>

typedef __bf16 bf16_t;
typedef bf16_t __attribute__((ext_vector_type(8))) bf16x8;
typedef float __attribute__((ext_vector_type(4))) f32x4;
typedef float __attribute__((ext_vector_type(16))) f32x16;
typedef unsigned u32;

#define BATCH 4
#define SEQ 1024
#define HIDD 1024
#define NH 16
#define DH 64

// ---------- helpers ----------
__device__ __forceinline__ unsigned short f2bf(float f) {
  unsigned u = __float_as_uint(f);
  u += 0x7fffu + ((u >> 16) & 1u);   // RNE
  return (unsigned short)(u >> 16);
}

__device__ __forceinline__ f32x4 mfma16(bf16x8 a, bf16x8 b, f32x4 c) {
  return __builtin_amdgcn_mfma_f32_16x16x32_bf16(a, b, c, 0, 0, 0);
}
__device__ __forceinline__ f32x16 mfma32(bf16x8 a, bf16x8 b, f32x16 c) {
  return __builtin_amdgcn_mfma_f32_32x32x16_bf16(a, b, c, 0, 0, 0);
}

__device__ __forceinline__ void gload_lds16(const void* g, void* l) {
  __builtin_amdgcn_global_load_lds(
      (__attribute__((address_space(1))) void*)(uintptr_t)g,
      (__attribute__((address_space(3))) void*)l, 16, 0, 0);
}

__device__ __forceinline__ u32 cvtpk(float lo, float hi) {
  u32 r;
  asm("v_cvt_pk_bf16_f32 %0, %1, %2" : "=v"(r) : "v"(lo), "v"(hi));
  return r;
}
__device__ __forceinline__ void plswap(u32& a, u32& b) {
  asm("v_permlane32_swap_b32 %0, %1" : "+v"(a), "+v"(b));
}

// ---------- kernel 1: hidden_states fp32 -> bf16 ----------
__global__ void hs2bf(const float* __restrict__ x, unsigned short* __restrict__ y) {
  const int i = blockIdx.x * 256 + threadIdx.x;
  const float4 f = ((const float4*)x)[i];
  ushort4 o = make_ushort4(f2bf(f.x), f2bf(f.y), f2bf(f.z), f2bf(f.w));
  ((ushort4*)y)[i] = o;
}

// ---------- kernel 2: W (K x N) fp32 -> Wt (N x K) bf16 ----------
__global__ __launch_bounds__(256) void wtrans(
    const float* __restrict__ Wq, const float* __restrict__ Wk,
    const float* __restrict__ Wv, unsigned short* __restrict__ Wt) {
  __shared__ unsigned short tile[64][72];
  const int z = blockIdx.z;
  const float* W = (z == 0) ? Wq : (z == 1) ? Wk : Wv;
  unsigned short* o = Wt + (size_t)z * (1024 * 1024);
  const int k0 = blockIdx.x * 64, n0 = blockIdx.y * 64;
  const int r = threadIdx.x >> 6, c = threadIdx.x & 63;
#pragma unroll
  for (int i = 0; i < 16; ++i) {
    const int row = i * 4 + r;
    tile[row][c] = f2bf(W[(size_t)(k0 + row) * 1024 + n0 + c]);
  }
  __syncthreads();
#pragma unroll
  for (int i = 0; i < 16; ++i) {
    const int row = i * 4 + r;
    o[(size_t)(n0 + row) * 1024 + k0 + c] = tile[c][row];
  }
}

// ---------- kernel 3: QKV projection GEMM ----------
__global__ __launch_bounds__(256) void qkv_gemm(
    const unsigned short* __restrict__ A,
    const unsigned short* __restrict__ Wt,
    const float* __restrict__ bq, const float* __restrict__ bk,
    const float* __restrict__ bv,
    unsigned short* __restrict__ outb) {
  __shared__ alignas(16) unsigned short Alds[128 * 32];
  __shared__ alignas(16) unsigned short Blds[128 * 32];

  const int z = blockIdx.z;
  const unsigned short* Bt = Wt + (size_t)z * (1024 * 1024);
  const float* bias = (z == 0) ? bq : (z == 1) ? bk : bv;
  unsigned short* outp = outb + (size_t)z * (4096 * 1024);
  const float scale = (z == 0) ? 0.125f * 1.44269504089f : 1.0f; // exp2 domain for Q

  const int m0 = blockIdx.x * 128;
  const int n0 = blockIdx.y * 128;
  const int t = threadIdx.x;
  const int w = t >> 6, l = t & 63;
  const int lg = l >> 4, lc = l & 15;
  const int wr = w >> 1, wc = w & 1;

  f32x4 acc[4][4] = {};

  for (int kt = 0; kt < 1024; kt += 32) {
    __syncthreads();
#pragma unroll
    for (int i = 0; i < 2; ++i) {
      const int c = i * 256 + t;
      const int row = c >> 2;
      const int kp = (c & 3) * 8;
      gload_lds16(A + (size_t)(m0 + row) * 1024 + kt + kp,
                  (char*)Alds + i * 4096 + w * 1024);
      gload_lds16(Bt + (size_t)(n0 + row) * 1024 + kt + kp,
                  (char*)Blds + i * 4096 + w * 1024);
    }
    __syncthreads();

    bf16x8 af[4], bfr[4];
#pragma unroll
    for (int m = 0; m < 4; ++m)
      af[m] = *(const bf16x8*)(Alds + (wr * 64 + m * 16 + lc) * 32 + lg * 8);
#pragma unroll
    for (int n = 0; n < 4; ++n)
      bfr[n] = *(const bf16x8*)(Blds + (wc * 64 + n * 16 + lc) * 32 + lg * 8);
#pragma unroll
    for (int m = 0; m < 4; ++m)
#pragma unroll
      for (int n = 0; n < 4; ++n)
        acc[m][n] = mfma16(af[m], bfr[n], acc[m][n]);
  }

#pragma unroll
  for (int n = 0; n < 4; ++n) {
    const int col = n0 + wc * 64 + n * 16 + lc;
    const float bs = bias[col];
#pragma unroll
    for (int m = 0; m < 4; ++m)
#pragma unroll
      for (int r = 0; r < 4; ++r) {
        const int row = m0 + wr * 64 + m * 16 + lg * 4 + r;
        outp[(size_t)row * 1024 + col] = f2bf((acc[m][n][r] + bs) * scale);
      }
  }
}

// ---------- kernel 3.5a: K (B,S,H,D) -> Kpack[bh][kb][s][lane] 16B chunks ----------
// chunk(bh,kb,s,l) = K[b, kb*32 + (l&31), h, s*16 + ((l>>5)&1)*8 .. +8]
// so attn's kf load (lane l) is contiguous: base + l*16B.
__global__ __launch_bounds__(256) void kpack_kernel(
    const unsigned short* __restrict__ K, unsigned short* __restrict__ Kp) {
  const int kb = blockIdx.x, bh = blockIdx.y;
  const int b = bh >> 4, h = bh & 15;
  const int t = threadIdx.x, l = t & 63, s = t >> 6;
  const unsigned short* src = K + (size_t)(b * 1024 + kb * 32 + (l & 31)) * 1024 +
                              h * 64 + s * 16 + ((l >> 5) & 1) * 8;
  const uint4 v = *(const uint4*)src;
  *(uint4*)(Kp + ((size_t)(bh * 32 + kb) * 4 + s) * 512 + l * 8) = v;
}

// ---------- kernel 3.5b: V (B,S,H,D) -> Vpack[bh][kt][g][s][lane] 16B chunks ----------
// chunk(bh,kt,g,s,l) = V[b, kt*64 + s*16 + ((l>>5)&1)*8 + e, h, g*32 + (l&31)]
// (= Vt[d = g*32+lo][key = kt*64 + s*16 + hi*8 + e], the PV B-fragment)
__global__ __launch_bounds__(256) void vpack_kernel(
    const unsigned short* __restrict__ V, unsigned short* __restrict__ Vp) {
  __shared__ unsigned short tile[64][72];  // [token_local][d]
  const int tt = blockIdx.x;   // 64-token tile
  const int hh = blockIdx.y;   // head
  const int t = threadIdx.x;
#pragma unroll
  for (int i = 0; i < 2; ++i) {
    const int c = i * 256 + t;
    const int row = c >> 3, cp = c & 7;
    *(uint4*)&tile[row][cp * 8] =
        *(const uint4*)(V + (size_t)(tt * 64 + row) * 1024 + hh * 64 + cp * 8);
  }
  __syncthreads();
  const int b = tt >> 4, kt = tt & 15;
  const int bh = b * 16 + hh;
#pragma unroll
  for (int i = 0; i < 2; ++i) {
    const int c = i * 256 + t;            // 512 chunks
    const int l = c & 63, s = (c >> 6) & 3, g = c >> 8;
    const int kl = s * 16 + ((l >> 5) & 1) * 8;
    const int d = g * 32 + (l & 31);
    unsigned short buf[8];
#pragma unroll
    for (int e = 0; e < 8; ++e) buf[e] = tile[kl + e][d];
    *(uint4*)(Vp + ((size_t)(bh * 16 + kt) * 8 + g * 4 + s) * 512 + l * 8) =
        *(uint4*)buf;
  }
}

// ---------- kernel 4: flash attention, packed-fragment global->register ----------
// grid 512 (XCD-swizzled); block 256 = 4 independent waves, each owns 32 q-rows.
// S^T = mfma32(K, Q^T): C col=lane&31=qrow, row=key=(reg&3)+8*(reg>>2)+4*(lane>>5).
// All inner-loop loads are lane-contiguous 1KB bursts from Kpack/Vpack.
__global__ __launch_bounds__(256, 2) void attn_kernel(
    const unsigned short* __restrict__ Qb,     // (B,S,H,D) bf16, pre-scaled log2e/sqrt(D)
    const unsigned short* __restrict__ Kpack,  // [bh][kb][s][lane] 16B
    const unsigned short* __restrict__ Vpack,  // [bh][kt][g][s][lane] 16B
    const int* __restrict__ amask,             // (B,S)
    const float* __restrict__ lhm,             // (H)
    float* __restrict__ out) {                 // (B,S,HID) fp32
  const int id = blockIdx.x;
  const int swzid = (id & 7) * 64 + (id >> 3);  // 8 bh per XCD
  const int qt = swzid & 7;
  const int bh = swzid >> 3;
  const int b = bh >> 4, h = bh & 15;
  const int t = threadIdx.x;
  const int w = t >> 6, l = t & 63;
  const int lo = l & 31, hi = l >> 5;
  const int q0 = qt * 128 + w * 32;

  // packed bases (both 65536 shorts per bh); lane offset folded in
  const unsigned short* Kp = Kpack + (size_t)bh * 65536 + l * 8;
  const unsigned short* Vp = Vpack + (size_t)bh * 65536 + l * 8;

  // Q fragments (B-op): lane holds Q[q0+lo][d = s*16 + hi*8 + e]
  const unsigned short* qp = Qb + (size_t)(b * SEQ + q0 + lo) * HIDD + h * DH + hi * 8;
  bf16x8 qf[4];
#pragma unroll
  for (int s = 0; s < 4; ++s) qf[s] = *(const bf16x8*)(qp + s * 16);

  // mask precheck: one pass over batch b's mask (common case: all ones)
  bool needmask;
  {
    unsigned long long mm = ~0ull;
#pragma unroll
    for (int tk = 0; tk < 16; ++tk)
      mm &= __ballot(amask[b * SEQ + tk * 64 + l] > 0);
    needmask = (mm != ~0ull);
  }

  float m_run = -INFINITY, l_run = 0.f;
  f32x16 acc0 = {}, acc1 = {};

  bf16x8 kf0[4], kf1[4], vf0[4], vf1[4];

  // prefetch K tile 0 (kb 0,1)
#pragma unroll
  for (int s = 0; s < 4; ++s) {
    kf0[s] = *(const bf16x8*)(Kp + (s)*512);
    kf1[s] = *(const bf16x8*)(Kp + (4 + s) * 512);
  }

  for (int tk = 0; tk < 16; ++tk) {
    // issue V loads for this tile (consumed after softmax -> latency hidden)
#pragma unroll
    for (int s = 0; s < 4; ++s) {
      vf0[s] = *(const bf16x8*)(Vp + (size_t)(tk * 8 + s) * 512);
      vf1[s] = *(const bf16x8*)(Vp + (size_t)(tk * 8 + 4 + s) * 512);
    }

    // ---- S^T = K . Q^T ----
    f32x16 sg0 = {}, sg1 = {};
    __builtin_amdgcn_s_setprio(1);
#pragma unroll
    for (int s = 0; s < 4; ++s) {
      sg0 = mfma32(kf0[s], qf[s], sg0);
      sg1 = mfma32(kf1[s], qf[s], sg1);
    }
    __builtin_amdgcn_s_setprio(0);

    // prefetch K for next tile (hidden under softmax + PV)
    if (tk < 15) {
#pragma unroll
      for (int s = 0; s < 4; ++s) {
        kf0[s] = *(const bf16x8*)(Kp + (size_t)(tk * 8 + 8 + s) * 512);
        kf1[s] = *(const bf16x8*)(Kp + (size_t)(tk * 8 + 12 + s) * 512);
      }
    }

    // ---- row max ----
    float t0[8];
#pragma unroll
    for (int i = 0; i < 8; ++i)
      t0[i] = fmaxf(fmaxf(sg0[i], sg0[i + 8]), fmaxf(sg1[i], sg1[i + 8]));
    float t1 = fmaxf(fmaxf(fmaxf(t0[0], t0[1]), fmaxf(t0[2], t0[3])),
                     fmaxf(fmaxf(t0[4], t0[5]), fmaxf(t0[6], t0[7])));
    const float pmax = fmaxf(t1, __shfl_xor(t1, 32));

    // ---- defer-max (T13) ----
    if (!__all(pmax <= m_run + 8.f)) {
      const float mnew = fmaxf(m_run, pmax);
      const float sc = __builtin_amdgcn_exp2f(m_run - mnew);
      m_run = mnew;
      l_run *= sc;
#pragma unroll
      for (int g = 0; g < 16; ++g) {
        const int rowi = (g & 3) + 8 * (g >> 2) + 4 * hi;
        const float scr = __shfl(sc, rowi);
        acc0[g] *= scr;
        acc1[g] *= scr;
      }
    }

    // ---- p = exp2(s - m) ----
#pragma unroll
    for (int g = 0; g < 16; ++g) {
      sg0[g] = __builtin_amdgcn_exp2f(sg0[g] - m_run);
      sg1[g] = __builtin_amdgcn_exp2f(sg1[g] - m_run);
    }

    // ---- mask (slow path only; softmax invariant to max ref) ----
    if (needmask) {
      const int mv = amask[b * SEQ + tk * 64 + l];
      const unsigned long long m64 = __ballot(mv > 0);
      if (m64 != ~0ull) {
#pragma unroll
        for (int g = 0; g < 16; ++g) {
          const int krow = (g & 3) + 8 * (g >> 2) + 4 * hi;
          if (!((m64 >> krow) & 1)) sg0[g] = 0.f;
          if (!((m64 >> (krow + 32)) & 1)) sg1[g] = 0.f;
        }
      }
    }

    // ---- row sum ----
    float s0[8];
#pragma unroll
    for (int i = 0; i < 8; ++i)
      s0[i] = (sg0[i] + sg0[i + 8]) + (sg1[i] + sg1[i + 8]);
    float rs = ((s0[0] + s0[1]) + (s0[2] + s0[3])) +
               ((s0[4] + s0[5]) + (s0[6] + s0[7]));
    rs += __shfl_xor(rs, 32);
    l_run += rs;

    // ---- P -> bf16 PA fragments in-register (T12) ----
    auto mk = [](float a0, float a1, float a2, float a3,
                 float a4, float a5, float a6, float a7) -> bf16x8 {
      u32 x = cvtpk(a0, a1), y = cvtpk(a2, a3);
      u32 a = cvtpk(a4, a5), b2 = cvtpk(a6, a7);
      plswap(x, a);
      plswap(y, b2);
      union { u32 u[4]; bf16x8 v; } fu;
      fu.u[0] = x; fu.u[1] = y; fu.u[2] = a; fu.u[3] = b2;
      return fu.v;
    };
    const bf16x8 pa0 = mk(sg0[0], sg0[1], sg0[2], sg0[3], sg0[4], sg0[5], sg0[6], sg0[7]);
    const bf16x8 pa1 = mk(sg0[8], sg0[9], sg0[10], sg0[11], sg0[12], sg0[13], sg0[14], sg0[15]);
    const bf16x8 pa2 = mk(sg1[0], sg1[1], sg1[2], sg1[3], sg1[4], sg1[5], sg1[6], sg1[7]);
    const bf16x8 pa3 = mk(sg1[8], sg1[9], sg1[10], sg1[11], sg1[12], sg1[13], sg1[14], sg1[15]);

    // ---- PV: acc += P . V ----
    __builtin_amdgcn_s_setprio(1);
#pragma unroll
    for (int s = 0; s < 4; ++s) {
      const bf16x8 paf = (s == 0) ? pa0 : (s == 1) ? pa1 : (s == 2) ? pa2 : pa3;
      acc0 = mfma32(paf, vf0[s], acc0);
      acc1 = mfma32(paf, vf1[s], acc1);
    }
    __builtin_amdgcn_s_setprio(0);
  }

  // ---- epilogue ----
  const float hm = lhm[h];
  const float inv = hm / l_run;
  float* ob = out + (size_t)(b * SEQ + q0) * HIDD + h * DH + lo;
#pragma unroll
  for (int g = 0; g < 16; ++g) {
    const int rowi = (g & 3) + 8 * (g >> 2) + 4 * hi;
    const float iv = __shfl(inv, rowi);
    ob[(size_t)rowi * HIDD] = acc0[g] * iv;
    ob[(size_t)rowi * HIDD + 32] = acc1[g] * iv;
  }
}

// ---------- launch ----------
extern "C" void kernel_launch(void* const* d_in, const int* in_sizes, int n_in,
                              void* d_out, int out_size, void* d_ws, size_t ws_size,
                              hipStream_t stream) {
  const float* hs = (const float*)d_in[0];
  const int* amask = (const int*)d_in[1];
  const float* lhm = (const float*)d_in[2];
  const float* Wq = (const float*)d_in[3];
  const float* bq = (const float*)d_in[4];
  const float* Wk = (const float*)d_in[5];
  const float* bk = (const float*)d_in[6];
  const float* Wv = (const float*)d_in[7];
  const float* bv = (const float*)d_in[8];
  float* out = (float*)d_out;

  char* ws = (char*)d_ws;
  unsigned short* HSbf = (unsigned short*)ws;                   // 8 MB (dead after gemm)
  unsigned short* Wt = (unsigned short*)(ws + (8u << 20));      // 6 MB
  unsigned short* QKV = (unsigned short*)(ws + (14u << 20));    // 24 MB
  unsigned short* Kpk = (unsigned short*)ws;                    // 8 MB, overlays HSbf
  unsigned short* Vpk = (unsigned short*)(ws + (38u << 20));    // 8 MB

  hs2bf<<<4096, 256, 0, stream>>>(hs, HSbf);
  wtrans<<<dim3(16, 16, 3), 256, 0, stream>>>(Wq, Wk, Wv, Wt);
  qkv_gemm<<<dim3(32, 8, 3), 256, 0, stream>>>(HSbf, Wt, bq, bk, bv, QKV);
  kpack_kernel<<<dim3(32, 64), 256, 0, stream>>>(QKV + (size_t)4096 * 1024, Kpk);
  vpack_kernel<<<dim3(64, 16), 256, 0, stream>>>(QKV + (size_t)2 * 4096 * 1024, Vpk);
  attn_kernel<<<512, 256, 0, stream>>>(QKV, Kpk, Vpk, amask, lhm, out);
}